// Round 2
// baseline (313.853 us; speedup 1.0000x reference)
//
#include <hip/hip_runtime.h>
#include <hip/hip_bf16.h>

typedef __hip_bfloat16 bf16;

// Broadcast lane l's float value to all lanes (wave-uniform, full exec).
static __device__ __forceinline__ float lane_bcast_f(float v, int l) {
    return __uint_as_float(__builtin_amdgcn_readlane(__float_as_uint(v), l));
}

// One wave per output row. lane = feature/column index (0..63).
// agg[row][lane] = mean_k feats[nid2[idx1[row][k]]][lane]
// h[row][lane]   = relu(b[lane] + sum_d agg[d] * W[d][lane])
// HT = storage type of the h1 intermediate (float preferred, bf16 fallback).
template <typename HT>
__global__ __launch_bounds__(256) void k_hop1(
    const float* __restrict__ feats,  // [V,64] fp32
    const float* __restrict__ W0,     // [64,64]
    const float* __restrict__ b0,     // [64]
    const int*   __restrict__ idx1,   // [N1,32]
    const int*   __restrict__ nid2,   // [N2]
    HT*          __restrict__ h1,     // [N1,64] out
    int N1)
{
    const int lane  = threadIdx.x & 63;
    const int gwave = blockIdx.x * (blockDim.x >> 6) + (threadIdx.x >> 6);
    const int nwave = gridDim.x * (blockDim.x >> 6);

    // Per-lane column of W0: w0[d] = W0[d][lane]
    float w0[64];
#pragma unroll
    for (int d = 0; d < 64; ++d) w0[d] = W0[d * 64 + lane];
    const float bias = b0[lane];

    for (int row = gwave; row < N1; row += nwave) {
        // lanes 0..31 hold the 32 neighbor indices (lanes 32..63 duplicate)
        const int j   = idx1[row * 32 + (lane & 31)];
        const int nid = nid2[j];

        float acc = 0.f;
#pragma unroll
        for (int k = 0; k < 32; ++k) {
            const int nk = __builtin_amdgcn_readlane(nid, k);     // wave-uniform row id
            acc += feats[(size_t)nk * 64 + lane];                  // coalesced 256B/row
        }
        const float agg = acc * 0.03125f;  // /32

        float h = bias;
#pragma unroll
        for (int d = 0; d < 64; ++d)
            h = fmaf(lane_bcast_f(agg, d), w0[d], h);
        h = fmaxf(h, 0.f);
        if constexpr (sizeof(HT) == 2)
            h1[(size_t)row * 64 + lane] = __float2bfloat16(h);
        else
            h1[(size_t)row * 64 + lane] = h;
    }
}

// Seed layer: gather-mean over h1 rows, then W1+b1+relu. Output fp32.
template <typename HT>
__global__ __launch_bounds__(256) void k_hop0(
    const HT*    __restrict__ h1,     // [N1,64]
    const float* __restrict__ W1,     // [64,64]
    const float* __restrict__ b1,     // [64]
    const int*   __restrict__ idx0,   // [N0,32]
    float*       __restrict__ out,    // [N0,64] fp32
    int N0)
{
    const int lane  = threadIdx.x & 63;
    const int gwave = blockIdx.x * (blockDim.x >> 6) + (threadIdx.x >> 6);
    const int nwave = gridDim.x * (blockDim.x >> 6);

    float w1[64];
#pragma unroll
    for (int d = 0; d < 64; ++d) w1[d] = W1[d * 64 + lane];
    const float bias = b1[lane];

    for (int row = gwave; row < N0; row += nwave) {
        const int j = idx0[row * 32 + (lane & 31)];

        float acc = 0.f;
#pragma unroll
        for (int k = 0; k < 32; ++k) {
            const int jk = __builtin_amdgcn_readlane(j, k);
            float v;
            if constexpr (sizeof(HT) == 2)
                v = __bfloat162float(h1[(size_t)jk * 64 + lane]);
            else
                v = h1[(size_t)jk * 64 + lane];
            acc += v;
        }
        const float agg = acc * 0.03125f;

        float o = bias;
#pragma unroll
        for (int d = 0; d < 64; ++d)
            o = fmaf(lane_bcast_f(agg, d), w1[d], o);
        o = fmaxf(o, 0.f);
        out[(size_t)row * 64 + lane] = o;
    }
}

extern "C" void kernel_launch(void* const* d_in, const int* in_sizes, int n_in,
                              void* d_out, int out_size, void* d_ws, size_t ws_size,
                              hipStream_t stream) {
    const float* feats = (const float*)d_in[0];
    const float* W0    = (const float*)d_in[1];
    const float* b0    = (const float*)d_in[2];
    const float* W1    = (const float*)d_in[3];
    const float* b1    = (const float*)d_in[4];
    const int*   idx0  = (const int*)d_in[5];   // [N0,32]
    const int*   idx1  = (const int*)d_in[6];   // [N1,32]
    // d_in[7] = node_ids1 — dead in the reference (v1 unused)
    const int*   nid2  = (const int*)d_in[8];   // [N2]

    const int N0 = in_sizes[5] / 32;            // 8192
    const int N1 = in_sizes[6] / 32;            // 100000

    const size_t need_f32 = (size_t)N1 * 64 * sizeof(float);   // 25.6 MB

    if (ws_size >= need_f32) {
        float* h1 = (float*)d_ws;
        k_hop1<float><<<2048, 256, 0, stream>>>(feats, W0, b0, idx1, nid2, h1, N1);
        k_hop0<float><<<512, 256, 0, stream>>>(h1, W1, b1, idx0, (float*)d_out, N0);
    } else {
        bf16* h1 = (bf16*)d_ws;                 // 12.8 MB fallback
        k_hop1<bf16><<<2048, 256, 0, stream>>>(feats, W0, b0, idx1, nid2, h1, N1);
        k_hop0<bf16><<<512, 256, 0, stream>>>(h1, W1, b1, idx0, (float*)d_out, N0);
    }
}